// Round 21
// baseline (240.156 us; speedup 1.0000x reference)
//
#include <hip/hip_runtime.h>

// ---------------------------------------------------------------------------
// TransformerBlock (B=2, T=2048, D=1024, H=16, DH=64, DFF=4096) on gfx950.
// Round 21: R20 (226us) + LDS-economy model applied to FF2 and QKV:
//   FF2: BM=128 + SPLITK=2 -> 512 blocks (2/CU), 512 B LDS per MFMA.
//   QKV: BM=128 -> 768 blocks (3/CU), 512 B/MFMA.
// (Model from R20: bytes-of-LDS-read per MFMA is the GEMM throughput lever
// once >=2 blocks/CU cover the 2-barrier staging; FF1-wide validated it.)
// ---------------------------------------------------------------------------

#define B_   2
#define T_   2048
#define D_   1024
#define H_   16
#define DH_  64
#define DFF_ 4096
#define M_   4096   // B_*T_

typedef __attribute__((ext_vector_type(8))) short short8;   // 8 x bf16
typedef __attribute__((ext_vector_type(4))) float f32x4;    // MFMA accumulator

__device__ __forceinline__ unsigned short f2bf(float f) {
    union { float f; unsigned int u; } x; x.f = f;
    return (unsigned short)((x.u + 0x7FFFu + ((x.u >> 16) & 1u)) >> 16); // RNE
}
__device__ __forceinline__ unsigned int f2bf_trunc_u(float f) {
    union { float f; unsigned int u; } x; x.f = f;
    return x.u >> 16;   // P is renormalized; trunc is fine
}

__device__ __forceinline__ void gload_lds16(const unsigned short* g, unsigned short* l) {
    __builtin_amdgcn_global_load_lds(
        (const __attribute__((address_space(1))) void*)g,
        (__attribute__((address_space(3))) void*)l, 16, 0, 0);
}

// Swizzled fragment pointer into a [rows][64] bf16 tile (128 B rows).
// Storage swizzle: byte = row*128 + (chunk16 ^ (row&7))*16.  Measured
// zero bank conflicts.
__device__ __forceinline__ const short8* swz_frag(const unsigned short* base, int row, int ks, int g) {
    int byte = row * 128 + ((ks * 64 + g * 16) ^ ((row & 7) << 4));
    return reinterpret_cast<const short8*>(reinterpret_cast<const char*>(base) + byte);
}

// ---------------------------------------------------------------------------
// LayerNorm: fp32 row (D=1024) -> bf16 row.
// ---------------------------------------------------------------------------
__global__ __launch_bounds__(256) void ln_kernel(
    const float* __restrict__ in, const float* __restrict__ sc,
    const float* __restrict__ bi, unsigned short* __restrict__ out)
{
    __shared__ float ls[4], lq[4];
    const int row = blockIdx.x, t = threadIdx.x;
    const float* rp = in + (size_t)row * D_;
    float4 v = *reinterpret_cast<const float4*>(rp + t * 4);
    float s  = v.x + v.y + v.z + v.w;
    float sq = v.x * v.x + v.y * v.y + v.z * v.z + v.w * v.w;
#pragma unroll
    for (int d = 32; d > 0; d >>= 1) {
        s  += __shfl_down(s, d);
        sq += __shfl_down(sq, d);
    }
    if ((t & 63) == 0) { ls[t >> 6] = s; lq[t >> 6] = sq; }
    __syncthreads();
    s  = ls[0] + ls[1] + ls[2] + ls[3];
    sq = lq[0] + lq[1] + lq[2] + lq[3];
    float mean = s * (1.f / D_);
    float var  = fmaxf(sq * (1.f / D_) - mean * mean, 0.f);
    float inv  = 1.f / (sqrtf(var) + 1e-5f);
    float4 scv = *reinterpret_cast<const float4*>(sc + t * 4);
    float4 biv = *reinterpret_cast<const float4*>(bi + t * 4);
    ushort4 ov;
    ov.x = f2bf((v.x - mean) * inv * scv.x + biv.x);
    ov.y = f2bf((v.y - mean) * inv * scv.y + biv.y);
    ov.z = f2bf((v.z - mean) * inv * scv.z + biv.z);
    ov.w = f2bf((v.w - mean) * inv * scv.w + biv.w);
    *reinterpret_cast<ushort4*>(out + (size_t)row * D_ + t * 4) = ov;
}

// ---------------------------------------------------------------------------
// Batched convert fp32 [1024][1024] -> bf16 transposed, z selects src/dst.
// ---------------------------------------------------------------------------
__global__ __launch_bounds__(256) void cvt_t4_kernel(
    const float* __restrict__ s0, const float* __restrict__ s1,
    const float* __restrict__ s2, const float* __restrict__ s3,
    unsigned short* __restrict__ d0, unsigned short* __restrict__ d1,
    unsigned short* __restrict__ d2, unsigned short* __restrict__ d3,
    float sc0)
{
    __shared__ unsigned short lds[64][66];
    const int z = blockIdx.z;
    const float* in = (z == 0) ? s0 : (z == 1) ? s1 : (z == 2) ? s2 : s3;
    unsigned short* out = (z == 0) ? d0 : (z == 1) ? d1 : (z == 2) ? d2 : d3;
    const float scale = (z == 0) ? sc0 : 1.f;
    const int r0 = blockIdx.x * 64, c0 = blockIdx.y * 64;
#pragma unroll
    for (int i = 0; i < 16; i++) {
        int idx = threadIdx.x + i * 256;
        int r = idx >> 6, c = idx & 63;
        lds[r][c] = f2bf(in[(size_t)(r0 + r) * 1024 + (c0 + c)] * scale);
    }
    __syncthreads();
#pragma unroll
    for (int i = 0; i < 16; i++) {
        int idx = threadIdx.x + i * 256;
        int r = idx >> 6, c = idx & 63;
        out[(size_t)(c0 + r) * 1024 + (r0 + c)] = lds[c][r];
    }
}

// ---------------------------------------------------------------------------
// Convert fp32 [R][C] -> bf16 transposed [C][R] (for w1, w2).
// ---------------------------------------------------------------------------
__global__ __launch_bounds__(256) void cvt_t_kernel(
    const float* __restrict__ in, unsigned short* __restrict__ out,
    int R, int C, float scale)
{
    __shared__ unsigned short lds[64][66];
    const int r0 = blockIdx.x * 64, c0 = blockIdx.y * 64;
#pragma unroll
    for (int i = 0; i < 16; i++) {
        int idx = threadIdx.x + i * 256;
        int r = idx >> 6, c = idx & 63;
        lds[r][c] = f2bf(in[(size_t)(r0 + r) * C + (c0 + c)] * scale);
    }
    __syncthreads();
#pragma unroll
    for (int i = 0; i < 16; i++) {
        int idx = threadIdx.x + i * 256;
        int r = idx >> 6, c = idx & 63;
        out[(size_t)(c0 + r) * R + (r0 + c)] = lds[c][r];
    }
}

// ---------------------------------------------------------------------------
// fp32 out[i] += partial[i]  (split-K reduce), float4 grid-stride.
// ---------------------------------------------------------------------------
__global__ __launch_bounds__(256) void addp_kernel(
    float* __restrict__ out, const float* __restrict__ p)
{
    const int n4 = (M_ * D_) / 4;
    int i = blockIdx.x * 256 + threadIdx.x;
    const int stride = gridDim.x * 256;
    for (; i < n4; i += stride) {
        float4 a = reinterpret_cast<float4*>(out)[i];
        float4 b = reinterpret_cast<const float4*>(p)[i];
        a.x += b.x; a.y += b.y; a.z += b.z; a.w += b.w;
        reinterpret_cast<float4*>(out)[i] = a;
    }
}

// ---------------------------------------------------------------------------
// FF1 GEMM: C[4096,4096] = A[4096,1024] x Bt[4096,1024]^T, bias + GELU.
// 256x128 tile, BK=64, single-buffer 48KB LDS, 256 thr = 4 waves, wave tile
// 64x128 (acc[4][8], 64 MFMA / 24 b128-reads per K-tile = 384 B/MFMA).
// Grid (16,32) = 512 blocks = 2 blocks/CU.
// ---------------------------------------------------------------------------
__global__ __launch_bounds__(256, 2) void gemm_ff1_wide(
    const unsigned short* __restrict__ A,
    const unsigned short* __restrict__ Bt,
    unsigned short* __restrict__ out,
    const float* __restrict__ bias)
{
    __shared__ __align__(16) unsigned short sA[256 * 64];   // 32 KB
    __shared__ __align__(16) unsigned short sB[128 * 64];   // 16 KB
    const int tid = threadIdx.x, lane = tid & 63, w = tid >> 6;
    const int bm = blockIdx.x * 256, bn = blockIdx.y * 128;
    const int wm = w * 64;
    const int rsel = lane & 15, g = lane >> 4;

    f32x4 acc[4][8];
#pragma unroll
    for (int m = 0; m < 4; m++)
#pragma unroll
        for (int n = 0; n < 8; n++) acc[m][n] = (f32x4){0.f, 0.f, 0.f, 0.f};

    for (int k0 = 0; k0 < 1024; k0 += 64) {
        __syncthreads();   // all waves done reading previous tile
#pragma unroll
        for (int i = 0; i < 8; i++) {
            int slot = i * 256 + tid;            // 0..2047
            int row = slot >> 3, ch = slot & 7;
            int sc = ch ^ (row & 7);
            gload_lds16(&A[(size_t)(bm + row) * 1024 + k0 + sc * 8], &sA[(i * 256 + w * 64) * 8]);
        }
#pragma unroll
        for (int i = 0; i < 4; i++) {
            int slot = i * 256 + tid;            // 0..1023
            int row = slot >> 3, ch = slot & 7;
            int sc = ch ^ (row & 7);
            gload_lds16(&Bt[(size_t)(bn + row) * 1024 + k0 + sc * 8], &sB[(i * 256 + w * 64) * 8]);
        }
        __syncthreads();   // drains vmcnt -> tile resident
#pragma unroll
        for (int ks = 0; ks < 2; ks++) {
            short8 a[4], b[8];
#pragma unroll
            for (int m = 0; m < 4; m++) a[m] = *swz_frag(sA, wm + m * 16 + rsel, ks, g);
#pragma unroll
            for (int n = 0; n < 8; n++) b[n] = *swz_frag(sB, n * 16 + rsel, ks, g);
#pragma unroll
            for (int m = 0; m < 4; m++)
#pragma unroll
                for (int n = 0; n < 8; n++)
                    acc[m][n] = __builtin_amdgcn_mfma_f32_16x16x32_bf16(a[m], b[n], acc[m][n], 0, 0, 0);
        }
    }

    const int rq = g * 4;
#pragma unroll
    for (int m = 0; m < 4; m++)
#pragma unroll
        for (int n = 0; n < 8; n++)
#pragma unroll
            for (int j = 0; j < 4; j++) {
                int rg = bm + wm + m * 16 + rq + j;
                int cg = bn + n * 16 + rsel;
                float v = acc[m][n][j] + bias[cg];
                float u = 0.7978845608028654f * (v + 0.044715f * v * v * v);
                float e = exp2f(2.8853900817779268f * u);
                v = v - v / (1.0f + e);
                out[(size_t)rg * DFF_ + cg] = f2bf(v);
            }
}

// ---------------------------------------------------------------------------
// GEMM C[M,N] = A[M,K] * B^T[N,K]  (bf16 "NT"), BMx128 tile, BK=64, 4 waves.
// DBUF=1: stage(next) before compute, ONE __syncthreads per iter.
// SPLITK>1: blockIdx.z selects K-slice; z=0 writes out(+bias+resid), z>0
// writes fp32 partial (reduced by addp_kernel).
// ---------------------------------------------------------------------------
enum { EPI_QKV3 = 0, EPI_BIAS_RES = 1, EPI_BIAS_GELU = 2 };

template <int EPI, int KDIM, int NDIM, int DBUF, int BM, int SPLITK>
__global__ __launch_bounds__(256) void gemm_nt(
    const unsigned short* __restrict__ A,
    const unsigned short* __restrict__ Bt,
    unsigned short* __restrict__ out0,
    unsigned short* __restrict__ out1,
    unsigned short* __restrict__ out2,
    float* __restrict__ outF,
    const float* __restrict__ bias,
    const float* __restrict__ resid,
    float* __restrict__ partial)
{
    constexpr int MF = BM / 32;        // m-fragments per wave
    constexpr int IA = BM / 32;        // A staging rounds
    constexpr int KLEN = KDIM / SPLITK;
    __shared__ __align__(16) unsigned short sA[DBUF + 1][BM * 64];
    __shared__ __align__(16) unsigned short sB[DBUF + 1][128 * 64];
    const int tid = threadIdx.x, lane = tid & 63, w = tid >> 6;
    const int bm = blockIdx.x * BM, bn = blockIdx.y * 128;
    const int kbeg = (SPLITK > 1) ? blockIdx.z * KLEN : 0;
    const int wm = (w >> 1) * (BM / 2), wn = (w & 1) * 64;
    const int rsel = lane & 15, g = lane >> 4;
    const int slot0 = w * 64 + lane;

    f32x4 acc[MF][4];
#pragma unroll
    for (int m = 0; m < MF; m++)
#pragma unroll
        for (int n = 0; n < 4; n++) acc[m][n] = (f32x4){0.f, 0.f, 0.f, 0.f};

    auto stage = [&](int buf, int k0) {
#pragma unroll
        for (int i = 0; i < IA; i++) {
            int slot = i * 256 + slot0;
            int row = slot >> 3, ch = slot & 7;
            int sc = ch ^ (row & 7);
            gload_lds16(&A[(size_t)(bm + row) * KDIM + k0 + sc * 8], &sA[buf][(i * 256 + w * 64) * 8]);
        }
#pragma unroll
        for (int i = 0; i < 4; i++) {
            int slot = i * 256 + slot0;
            int row = slot >> 3, ch = slot & 7;
            int sc = ch ^ (row & 7);
            gload_lds16(&Bt[(size_t)(bn + row) * KDIM + k0 + sc * 8], &sB[buf][(i * 256 + w * 64) * 8]);
        }
    };

    auto compute = [&](int buf) {
#pragma unroll
        for (int ks = 0; ks < 2; ks++) {
            short8 a[MF], b[4];
#pragma unroll
            for (int m = 0; m < MF; m++) a[m] = *swz_frag(sA[buf], wm + m * 16 + rsel, ks, g);
#pragma unroll
            for (int n = 0; n < 4; n++) b[n] = *swz_frag(sB[buf], wn + n * 16 + rsel, ks, g);
#pragma unroll
            for (int m = 0; m < MF; m++)
#pragma unroll
                for (int n = 0; n < 4; n++)
                    acc[m][n] = __builtin_amdgcn_mfma_f32_16x16x32_bf16(a[m], b[n], acc[m][n], 0, 0, 0);
        }
    };

    if constexpr (DBUF) {
        constexpr int NK = KLEN / 64;
        int cur = 0;
        stage(0, kbeg);
        __syncthreads();
        for (int kt = 0; kt < NK; ++kt) {
            if (kt + 1 < NK) stage(cur ^ 1, kbeg + (kt + 1) * 64);
            compute(cur);
            __syncthreads();  // drain lands after compute: latency hidden
            cur ^= 1;
        }
    } else {
        for (int k0 = kbeg; k0 < kbeg + KLEN; k0 += 64) {
            __syncthreads();
            stage(0, k0);
            __syncthreads();
            compute(0);
        }
    }

    const int rq = g * 4;
#pragma unroll
    for (int m = 0; m < MF; m++)
#pragma unroll
        for (int n = 0; n < 4; n++)
#pragma unroll
            for (int j = 0; j < 4; j++) {
                int rg = bm + wm + m * 16 + rq + j;   // global row (B*T)
                int cg = bn + wn + n * 16 + rsel;     // global col
                float v = acc[m][n][j];
                if constexpr (EPI == EPI_QKV3) {
                    int which = cg >> 10, col = cg & 1023;
                    int h = col >> 6, dh = col & 63;
                    int bb = rg >> 11, t = rg & 2047;
                    if (which == 0)
                        out0[(((size_t)(bb * H_ + h)) * T_ + t) * DH_ + dh] = f2bf(v);
                    else if (which == 1)
                        out1[(((size_t)(bb * H_ + h)) * T_ + t) * DH_ + dh] = f2bf(v);
                    else
                        out2[(((size_t)(bb * H_ + h)) * DH_ + dh) * T_ + t] = f2bf(v);
                } else if constexpr (EPI == EPI_BIAS_RES) {
                    if (SPLITK > 1 && blockIdx.z != 0) {
                        partial[(size_t)rg * NDIM + cg] = v;
                    } else {
                        v += bias[cg] + resid[(size_t)rg * NDIM + cg];
                        outF[(size_t)rg * NDIM + cg] = v;
                    }
                } else {
                    // fast GELU (tanh form via exp2)
                    v += bias[cg];
                    float u = 0.7978845608028654f * (v + 0.044715f * v * v * v);
                    float e = exp2f(2.8853900817779268f * u);
                    v = v - v / (1.0f + e);
                    out0[(size_t)rg * NDIM + cg] = f2bf(v);
                }
            }
}

// ---------------------------------------------------------------------------
// Causal flash attention, swapped-QK^T (max-free exp2 softmax).
// ---------------------------------------------------------------------------
__global__ __launch_bounds__(256, 4) void attn_kernel(
    const unsigned short* __restrict__ q,
    const unsigned short* __restrict__ k,
    const unsigned short* __restrict__ vt,
    unsigned short* __restrict__ o)
{
    __shared__ __align__(16) unsigned short sK[2][64 * 64];   // 16 KB
    __shared__ __align__(16) unsigned short sV[2][64 * 64];   // 16 KB
    __shared__ __align__(16) unsigned short pl[4][1024];      //  8 KB
    const int tid = threadIdx.x, lane = tid & 63, w = tid >> 6;

    // XCD-aware balanced remap
    const int x = blockIdx.x & 7, jb = blockIdx.x >> 3;
    const int bhl = jb & 3, ss = (jb >> 2) & 7, rr = jb >> 5;
    const int qt = (rr == 0) ? ss : (rr == 1) ? 15 - ss : (rr == 2) ? 16 + ss : 31 - ss;
    const int bh = x * 4 + bhl;

    const int qbase = qt * 64 + w * 16;
    const unsigned short* qp = q  + (size_t)bh * T_ * DH_;
    const unsigned short* kp = k  + (size_t)bh * T_ * DH_;
    const unsigned short* vp = vt + (size_t)bh * DH_ * T_;
    const int rsel = lane & 15, g = lane >> 4, koff = g * 8;
    const int slot0 = w * 64 + lane;
    const int swz = (rsel & 7) << 4;

    short8 bq[2];
#pragma unroll
    for (int ks = 0; ks < 2; ks++)
        bq[ks] = *reinterpret_cast<const short8*>(
            &qp[(size_t)(qbase + rsel) * DH_ + ks * 32 + koff]);

    float lr = 0.f;
    f32x4 oacc[4];
#pragma unroll
    for (int n = 0; n < 4; n++) oacc[n] = (f32x4){0.f, 0.f, 0.f, 0.f};

    const int nt = qt + 1;
    int cur = 0;

    auto stage = [&](int buf, int kv0) {
#pragma unroll
        for (int i = 0; i < 2; i++) {
            int slot = i * 256 + slot0;
            int row = slot >> 3, ch = slot & 7;
            int sc = ch ^ (row & 7);
            gload_lds16(&kp[(size_t)(kv0 + row) * DH_ + sc * 8], &sK[buf][(i * 256 + w * 64) * 8]);
            gload_lds16(&vp[(size_t)row * T_ + kv0 + sc * 8],    &sV[buf][(i * 256 + w * 64) * 8]);
        }
    };

    stage(0, 0);
    __syncthreads();

    unsigned short* plw = pl[w];
    for (int t = 0; t < nt; ++t) {
        const int kv0 = t * 64;
        if (t + 1 < nt) stage(cur ^ 1, (t + 1) * 64);
        f32x4 s4[4];
#pragma unroll
        for (int sub = 0; sub < 4; sub++) {
            short8 ak0 = *swz_frag(sK[cur], sub * 16 + rsel, 0, g);
            short8 ak1 = *swz_frag(sK[cur], sub * 16 + rsel, 1, g);
            f32x4 t0 = (f32x4){0.f, 0.f, 0.f, 0.f};
            t0 = __builtin_amdgcn_mfma_f32_16x16x32_bf16(ak0, bq[0], t0, 0, 0, 0);
            t0 = __builtin_amdgcn_mfma_f32_16x16x32_bf16(ak1, bq[1], t0, 0, 0, 0);
            s4[sub] = t0;
        }
        const int qg = qbase + rsel;
        if (t == nt - 1) {
#pragma unroll
            for (int sub = 0; sub < 4; sub++)
#pragma unroll
                for (int jj = 0; jj < 4; jj++) {
                    int kvg = kv0 + sub * 16 + g * 4 + jj;
                    if (kvg > qg) s4[sub][jj] = -1e30f;
                }
        }
#pragma unroll
        for (int sub = 0; sub < 4; sub++) {
            float p0 = exp2f(s4[sub][0]);
            float p1 = exp2f(s4[sub][1]);
            float p2 = exp2f(s4[sub][2]);
            float p3 = exp2f(s4[sub][3]);
            lr += (p0 + p1) + (p2 + p3);
            uint2 pk;
            pk.x = f2bf_trunc_u(p0) | (f2bf_trunc_u(p1) << 16);
            pk.y = f2bf_trunc_u(p2) | (f2bf_trunc_u(p3) << 16);
            int byte = rsel * 128 + ((sub * 32 + g * 8) ^ swz);
            *reinterpret_cast<uint2*>(reinterpret_cast<char*>(plw) + byte) = pk;
        }
#pragma unroll
        for (int ks = 0; ks < 2; ks++) {
            int rbyte = rsel * 128 + ((ks * 64 + g * 16) ^ swz);
            short8 bp = *reinterpret_cast<const short8*>(
                reinterpret_cast<const char*>(plw) + rbyte);
#pragma unroll
            for (int n = 0; n < 4; n++) {
                short8 av = *swz_frag(sV[cur], n * 16 + rsel, ks, g);
                oacc[n] = __builtin_amdgcn_mfma_f32_16x16x32_bf16(av, bp, oacc[n], 0, 0, 0);
            }
        }
        __syncthreads();
        cur ^= 1;
    }

    lr += __shfl_xor(lr, 16);
    lr += __shfl_xor(lr, 32);
    float inv = 1.0f / lr;
    const int bb = bh >> 4, h = bh & 15;
    const int rg = qbase + rsel;
    unsigned short* ob = o + ((size_t)(bb * T_ + rg)) * D_ + h * DH_ + g * 4;
#pragma unroll
    for (int n = 0; n < 4; n++) {
        uint2 pk;
        pk.x = (unsigned)f2bf(oacc[n][0] * inv) | ((unsigned)f2bf(oacc[n][1] * inv) << 16);
        pk.y = (unsigned)f2bf(oacc[n][2] * inv) | ((unsigned)f2bf(oacc[n][3] * inv) << 16);
        *reinterpret_cast<uint2*>(ob + n * 16) = pk;
    }
}

// ---------------------------------------------------------------------------
// Launch sequence
// ---------------------------------------------------------------------------
extern "C" void kernel_launch(void* const* d_in, const int* in_sizes, int n_in,
                              void* d_out, int out_size, void* d_ws, size_t ws_size,
                              hipStream_t stream)
{
    const float* x    = (const float*)d_in[0];
    const float* wq   = (const float*)d_in[1];
    const float* wk   = (const float*)d_in[2];
    const float* wv   = (const float*)d_in[3];
    const float* wo   = (const float*)d_in[4];
    const float* bo   = (const float*)d_in[5];
    const float* w1   = (const float*)d_in[6];
    const float* b1   = (const float*)d_in[7];
    const float* w2   = (const float*)d_in[8];
    const float* b2   = (const float*)d_in[9];
    const float* ln1s = (const float*)d_in[10];
    const float* ln1b = (const float*)d_in[11];
    const float* ln2s = (const float*)d_in[12];
    const float* ln2b = (const float*)d_in[13];
    float* out = (float*)d_out;

    char* ws = (char*)d_ws;
    unsigned short* wqkv_t = (unsigned short*)ws;                     // [3072][1024]
    unsigned short* wo_t   = wqkv_t + (size_t)3072 * 1024;            // [1024][1024]
    unsigned short* w1_t   = wo_t   + (size_t)1024 * 1024;            // [4096][1024]
    unsigned short* w2_t   = w1_t   + (size_t)4096 * 1024;            // [1024][4096]
    unsigned short* hbuf   = w2_t   + (size_t)1024 * 4096;            // [4096][1024]
    unsigned short* qb     = hbuf   + (size_t)4096 * 1024;            // (B,H,T,DH)
    unsigned short* kb     = qb     + (size_t)32 * 2048 * 64;
    unsigned short* vtb    = kb     + (size_t)32 * 2048 * 64;         // (B,H,DH,T)
    unsigned short* ao     = vtb    + (size_t)32 * 64 * 2048;         // (B,T,D)
    unsigned short* f1     = qb;    // reuse q|k|vt|ao span after attention+WO
    float* fpart = (float*)ws;      // overlays dead wqkv_t..w1_t at FF2 time

    // weight converts (wq folded with 0.125 * log2(e) for exp2-domain softmax)
    cvt_t4_kernel<<<dim3(16, 16, 4), 256, 0, stream>>>(
        wq, wk, wv, wo,
        wqkv_t, wqkv_t + 1024 * 1024, wqkv_t + 2 * 1024 * 1024, wo_t,
        0.180336880111120425f);
    cvt_t_kernel<<<dim3(16, 64), 256, 0, stream>>>(w1, w1_t, 1024, 4096, 1.f);
    cvt_t_kernel<<<dim3(64, 16), 256, 0, stream>>>(w2, w2_t, 4096, 1024, 1.f);

    // attention sublayer
    ln_kernel<<<M_, 256, 0, stream>>>(x, ln1s, ln1b, hbuf);
    gemm_nt<EPI_QKV3, 1024, 3072, 0, 128, 1><<<dim3(32, 24), 256, 0, stream>>>(
        hbuf, wqkv_t, qb, kb, vtb, nullptr, nullptr, nullptr, nullptr);
    attn_kernel<<<1024, 256, 0, stream>>>(qb, kb, vtb, ao);
    gemm_nt<EPI_BIAS_RES, 1024, 1024, 1, 64, 1><<<dim3(64, 8), 256, 0, stream>>>(
        ao, wo_t, nullptr, nullptr, nullptr, out, bo, x, nullptr);   // out = x2
    // feed-forward sublayer
    ln_kernel<<<M_, 256, 0, stream>>>(out, ln2s, ln2b, hbuf);
    gemm_ff1_wide<<<dim3(16, 32), 256, 0, stream>>>(hbuf, w1_t, f1, b1);
    gemm_nt<EPI_BIAS_RES, 4096, 1024, 0, 128, 2><<<dim3(32, 8, 2), 256, 0, stream>>>(
        f1, w2_t, nullptr, nullptr, nullptr, out, b2, out, fpart);   // z=0: out, z=1: fpart
    addp_kernel<<<2048, 256, 0, stream>>>(out, fpart);               // out += fpart
}

// Round 22
// 225.488 us; speedup vs baseline: 1.0651x; 1.0651x over previous
//
#include <hip/hip_runtime.h>

// ---------------------------------------------------------------------------
// TransformerBlock (B=2, T=2048, D=1024, H=16, DH=64, DFF=4096) on gfx950.
// Round 22: revert R21 (BM=128 for QKV/FF2 regressed: residency halved,
// barrier exposure doubled). Exact R20 configuration = measured optimum
// (226.0us): QKV/FF2 BM=64 (6/4 blocks per CU), WO BM=64 dbuf, FF1-wide
// 256x128 (375 B/MFMA at 2 blocks/CU), swapped-QK^T max-free attn.
// Model (final): bytes-of-LDS-per-MFMA matters only at constant blocks/CU;
// MFMA-per-barrier amortization and residency jointly gate all variants.
// ---------------------------------------------------------------------------

#define B_   2
#define T_   2048
#define D_   1024
#define H_   16
#define DH_  64
#define DFF_ 4096
#define M_   4096   // B_*T_

typedef __attribute__((ext_vector_type(8))) short short8;   // 8 x bf16
typedef __attribute__((ext_vector_type(4))) float f32x4;    // MFMA accumulator

__device__ __forceinline__ unsigned short f2bf(float f) {
    union { float f; unsigned int u; } x; x.f = f;
    return (unsigned short)((x.u + 0x7FFFu + ((x.u >> 16) & 1u)) >> 16); // RNE
}
__device__ __forceinline__ unsigned int f2bf_trunc_u(float f) {
    union { float f; unsigned int u; } x; x.f = f;
    return x.u >> 16;   // P is renormalized; trunc is fine
}

__device__ __forceinline__ void gload_lds16(const unsigned short* g, unsigned short* l) {
    __builtin_amdgcn_global_load_lds(
        (const __attribute__((address_space(1))) void*)g,
        (__attribute__((address_space(3))) void*)l, 16, 0, 0);
}

// Swizzled fragment pointer into a [rows][64] bf16 tile (128 B rows).
// Storage swizzle: byte = row*128 + (chunk16 ^ (row&7))*16.  Measured
// zero bank conflicts.
__device__ __forceinline__ const short8* swz_frag(const unsigned short* base, int row, int ks, int g) {
    int byte = row * 128 + ((ks * 64 + g * 16) ^ ((row & 7) << 4));
    return reinterpret_cast<const short8*>(reinterpret_cast<const char*>(base) + byte);
}

// ---------------------------------------------------------------------------
// LayerNorm: fp32 row (D=1024) -> bf16 row.
// ---------------------------------------------------------------------------
__global__ __launch_bounds__(256) void ln_kernel(
    const float* __restrict__ in, const float* __restrict__ sc,
    const float* __restrict__ bi, unsigned short* __restrict__ out)
{
    __shared__ float ls[4], lq[4];
    const int row = blockIdx.x, t = threadIdx.x;
    const float* rp = in + (size_t)row * D_;
    float4 v = *reinterpret_cast<const float4*>(rp + t * 4);
    float s  = v.x + v.y + v.z + v.w;
    float sq = v.x * v.x + v.y * v.y + v.z * v.z + v.w * v.w;
#pragma unroll
    for (int d = 32; d > 0; d >>= 1) {
        s  += __shfl_down(s, d);
        sq += __shfl_down(sq, d);
    }
    if ((t & 63) == 0) { ls[t >> 6] = s; lq[t >> 6] = sq; }
    __syncthreads();
    s  = ls[0] + ls[1] + ls[2] + ls[3];
    sq = lq[0] + lq[1] + lq[2] + lq[3];
    float mean = s * (1.f / D_);
    float var  = fmaxf(sq * (1.f / D_) - mean * mean, 0.f);
    float inv  = 1.f / (sqrtf(var) + 1e-5f);
    float4 scv = *reinterpret_cast<const float4*>(sc + t * 4);
    float4 biv = *reinterpret_cast<const float4*>(bi + t * 4);
    ushort4 ov;
    ov.x = f2bf((v.x - mean) * inv * scv.x + biv.x);
    ov.y = f2bf((v.y - mean) * inv * scv.y + biv.y);
    ov.z = f2bf((v.z - mean) * inv * scv.z + biv.z);
    ov.w = f2bf((v.w - mean) * inv * scv.w + biv.w);
    *reinterpret_cast<ushort4*>(out + (size_t)row * D_ + t * 4) = ov;
}

// ---------------------------------------------------------------------------
// Batched convert fp32 [1024][1024] -> bf16 transposed, z selects src/dst.
// ---------------------------------------------------------------------------
__global__ __launch_bounds__(256) void cvt_t4_kernel(
    const float* __restrict__ s0, const float* __restrict__ s1,
    const float* __restrict__ s2, const float* __restrict__ s3,
    unsigned short* __restrict__ d0, unsigned short* __restrict__ d1,
    unsigned short* __restrict__ d2, unsigned short* __restrict__ d3,
    float sc0)
{
    __shared__ unsigned short lds[64][66];
    const int z = blockIdx.z;
    const float* in = (z == 0) ? s0 : (z == 1) ? s1 : (z == 2) ? s2 : s3;
    unsigned short* out = (z == 0) ? d0 : (z == 1) ? d1 : (z == 2) ? d2 : d3;
    const float scale = (z == 0) ? sc0 : 1.f;
    const int r0 = blockIdx.x * 64, c0 = blockIdx.y * 64;
#pragma unroll
    for (int i = 0; i < 16; i++) {
        int idx = threadIdx.x + i * 256;
        int r = idx >> 6, c = idx & 63;
        lds[r][c] = f2bf(in[(size_t)(r0 + r) * 1024 + (c0 + c)] * scale);
    }
    __syncthreads();
#pragma unroll
    for (int i = 0; i < 16; i++) {
        int idx = threadIdx.x + i * 256;
        int r = idx >> 6, c = idx & 63;
        out[(size_t)(c0 + r) * 1024 + (r0 + c)] = lds[c][r];
    }
}

// ---------------------------------------------------------------------------
// Convert fp32 [R][C] -> bf16 transposed [C][R] (for w1, w2).
// ---------------------------------------------------------------------------
__global__ __launch_bounds__(256) void cvt_t_kernel(
    const float* __restrict__ in, unsigned short* __restrict__ out,
    int R, int C, float scale)
{
    __shared__ unsigned short lds[64][66];
    const int r0 = blockIdx.x * 64, c0 = blockIdx.y * 64;
#pragma unroll
    for (int i = 0; i < 16; i++) {
        int idx = threadIdx.x + i * 256;
        int r = idx >> 6, c = idx & 63;
        lds[r][c] = f2bf(in[(size_t)(r0 + r) * C + (c0 + c)] * scale);
    }
    __syncthreads();
#pragma unroll
    for (int i = 0; i < 16; i++) {
        int idx = threadIdx.x + i * 256;
        int r = idx >> 6, c = idx & 63;
        out[(size_t)(c0 + r) * R + (r0 + c)] = lds[c][r];
    }
}

// ---------------------------------------------------------------------------
// fp32 out[i] += partial[i]  (split-K reduce), float4 grid-stride.
// ---------------------------------------------------------------------------
__global__ __launch_bounds__(256) void addp_kernel(
    float* __restrict__ out, const float* __restrict__ p)
{
    const int n4 = (M_ * D_) / 4;
    int i = blockIdx.x * 256 + threadIdx.x;
    const int stride = gridDim.x * 256;
    for (; i < n4; i += stride) {
        float4 a = reinterpret_cast<float4*>(out)[i];
        float4 b = reinterpret_cast<const float4*>(p)[i];
        a.x += b.x; a.y += b.y; a.z += b.z; a.w += b.w;
        reinterpret_cast<float4*>(out)[i] = a;
    }
}

// ---------------------------------------------------------------------------
// FF1 GEMM: C[4096,4096] = A[4096,1024] x Bt[4096,1024]^T, bias + GELU.
// 256x128 tile, BK=64, single-buffer 48KB LDS, 256 thr = 4 waves, wave tile
// 64x128 (acc[4][8], 64 MFMA / 12 b128-reads per K-step = 375 B/MFMA).
// Grid (16,32) = 512 blocks = 2 blocks/CU.
// ---------------------------------------------------------------------------
__global__ __launch_bounds__(256, 2) void gemm_ff1_wide(
    const unsigned short* __restrict__ A,
    const unsigned short* __restrict__ Bt,
    unsigned short* __restrict__ out,
    const float* __restrict__ bias)
{
    __shared__ __align__(16) unsigned short sA[256 * 64];   // 32 KB
    __shared__ __align__(16) unsigned short sB[128 * 64];   // 16 KB
    const int tid = threadIdx.x, lane = tid & 63, w = tid >> 6;
    const int bm = blockIdx.x * 256, bn = blockIdx.y * 128;
    const int wm = w * 64;
    const int rsel = lane & 15, g = lane >> 4;

    f32x4 acc[4][8];
#pragma unroll
    for (int m = 0; m < 4; m++)
#pragma unroll
        for (int n = 0; n < 8; n++) acc[m][n] = (f32x4){0.f, 0.f, 0.f, 0.f};

    for (int k0 = 0; k0 < 1024; k0 += 64) {
        __syncthreads();   // all waves done reading previous tile
#pragma unroll
        for (int i = 0; i < 8; i++) {
            int slot = i * 256 + tid;            // 0..2047
            int row = slot >> 3, ch = slot & 7;
            int sc = ch ^ (row & 7);
            gload_lds16(&A[(size_t)(bm + row) * 1024 + k0 + sc * 8], &sA[(i * 256 + w * 64) * 8]);
        }
#pragma unroll
        for (int i = 0; i < 4; i++) {
            int slot = i * 256 + tid;            // 0..1023
            int row = slot >> 3, ch = slot & 7;
            int sc = ch ^ (row & 7);
            gload_lds16(&Bt[(size_t)(bn + row) * 1024 + k0 + sc * 8], &sB[(i * 256 + w * 64) * 8]);
        }
        __syncthreads();   // drains vmcnt -> tile resident
#pragma unroll
        for (int ks = 0; ks < 2; ks++) {
            short8 a[4], b[8];
#pragma unroll
            for (int m = 0; m < 4; m++) a[m] = *swz_frag(sA, wm + m * 16 + rsel, ks, g);
#pragma unroll
            for (int n = 0; n < 8; n++) b[n] = *swz_frag(sB, n * 16 + rsel, ks, g);
#pragma unroll
            for (int m = 0; m < 4; m++)
#pragma unroll
                for (int n = 0; n < 8; n++)
                    acc[m][n] = __builtin_amdgcn_mfma_f32_16x16x32_bf16(a[m], b[n], acc[m][n], 0, 0, 0);
        }
    }

    const int rq = g * 4;
#pragma unroll
    for (int m = 0; m < 4; m++)
#pragma unroll
        for (int n = 0; n < 8; n++)
#pragma unroll
            for (int j = 0; j < 4; j++) {
                int rg = bm + wm + m * 16 + rq + j;
                int cg = bn + n * 16 + rsel;
                float v = acc[m][n][j] + bias[cg];
                float u = 0.7978845608028654f * (v + 0.044715f * v * v * v);
                float e = exp2f(2.8853900817779268f * u);
                v = v - v / (1.0f + e);
                out[(size_t)rg * DFF_ + cg] = f2bf(v);
            }
}

// ---------------------------------------------------------------------------
// GEMM C[M,N] = A[M,K] * B^T[N,K]  (bf16 "NT"), BMx128 tile, BK=64, 4 waves.
// DBUF=1: stage(next) before compute, ONE __syncthreads per iter.
// SPLITK>1: blockIdx.z selects K-slice; z=0 writes out(+bias+resid), z>0
// writes fp32 partial (reduced by addp_kernel).
// ---------------------------------------------------------------------------
enum { EPI_QKV3 = 0, EPI_BIAS_RES = 1, EPI_BIAS_GELU = 2 };

template <int EPI, int KDIM, int NDIM, int DBUF, int BM, int SPLITK>
__global__ __launch_bounds__(256) void gemm_nt(
    const unsigned short* __restrict__ A,
    const unsigned short* __restrict__ Bt,
    unsigned short* __restrict__ out0,
    unsigned short* __restrict__ out1,
    unsigned short* __restrict__ out2,
    float* __restrict__ outF,
    const float* __restrict__ bias,
    const float* __restrict__ resid,
    float* __restrict__ partial)
{
    constexpr int MF = BM / 32;        // m-fragments per wave
    constexpr int IA = BM / 32;        // A staging rounds
    constexpr int KLEN = KDIM / SPLITK;
    __shared__ __align__(16) unsigned short sA[DBUF + 1][BM * 64];
    __shared__ __align__(16) unsigned short sB[DBUF + 1][128 * 64];
    const int tid = threadIdx.x, lane = tid & 63, w = tid >> 6;
    const int bm = blockIdx.x * BM, bn = blockIdx.y * 128;
    const int kbeg = (SPLITK > 1) ? blockIdx.z * KLEN : 0;
    const int wm = (w >> 1) * (BM / 2), wn = (w & 1) * 64;
    const int rsel = lane & 15, g = lane >> 4;
    const int slot0 = w * 64 + lane;

    f32x4 acc[MF][4];
#pragma unroll
    for (int m = 0; m < MF; m++)
#pragma unroll
        for (int n = 0; n < 4; n++) acc[m][n] = (f32x4){0.f, 0.f, 0.f, 0.f};

    auto stage = [&](int buf, int k0) {
#pragma unroll
        for (int i = 0; i < IA; i++) {
            int slot = i * 256 + slot0;
            int row = slot >> 3, ch = slot & 7;
            int sc = ch ^ (row & 7);
            gload_lds16(&A[(size_t)(bm + row) * KDIM + k0 + sc * 8], &sA[buf][(i * 256 + w * 64) * 8]);
        }
#pragma unroll
        for (int i = 0; i < 4; i++) {
            int slot = i * 256 + slot0;
            int row = slot >> 3, ch = slot & 7;
            int sc = ch ^ (row & 7);
            gload_lds16(&Bt[(size_t)(bn + row) * KDIM + k0 + sc * 8], &sB[buf][(i * 256 + w * 64) * 8]);
        }
    };

    auto compute = [&](int buf) {
#pragma unroll
        for (int ks = 0; ks < 2; ks++) {
            short8 a[MF], b[4];
#pragma unroll
            for (int m = 0; m < MF; m++) a[m] = *swz_frag(sA[buf], wm + m * 16 + rsel, ks, g);
#pragma unroll
            for (int n = 0; n < 4; n++) b[n] = *swz_frag(sB[buf], wn + n * 16 + rsel, ks, g);
#pragma unroll
            for (int m = 0; m < MF; m++)
#pragma unroll
                for (int n = 0; n < 4; n++)
                    acc[m][n] = __builtin_amdgcn_mfma_f32_16x16x32_bf16(a[m], b[n], acc[m][n], 0, 0, 0);
        }
    };

    if constexpr (DBUF) {
        constexpr int NK = KLEN / 64;
        int cur = 0;
        stage(0, kbeg);
        __syncthreads();
        for (int kt = 0; kt < NK; ++kt) {
            if (kt + 1 < NK) stage(cur ^ 1, kbeg + (kt + 1) * 64);
            compute(cur);
            __syncthreads();  // drain lands after compute: latency hidden
            cur ^= 1;
        }
    } else {
        for (int k0 = kbeg; k0 < kbeg + KLEN; k0 += 64) {
            __syncthreads();
            stage(0, k0);
            __syncthreads();
            compute(0);
        }
    }

    const int rq = g * 4;
#pragma unroll
    for (int m = 0; m < MF; m++)
#pragma unroll
        for (int n = 0; n < 4; n++)
#pragma unroll
            for (int j = 0; j < 4; j++) {
                int rg = bm + wm + m * 16 + rq + j;   // global row (B*T)
                int cg = bn + wn + n * 16 + rsel;     // global col
                float v = acc[m][n][j];
                if constexpr (EPI == EPI_QKV3) {
                    int which = cg >> 10, col = cg & 1023;
                    int h = col >> 6, dh = col & 63;
                    int bb = rg >> 11, t = rg & 2047;
                    if (which == 0)
                        out0[(((size_t)(bb * H_ + h)) * T_ + t) * DH_ + dh] = f2bf(v);
                    else if (which == 1)
                        out1[(((size_t)(bb * H_ + h)) * T_ + t) * DH_ + dh] = f2bf(v);
                    else
                        out2[(((size_t)(bb * H_ + h)) * DH_ + dh) * T_ + t] = f2bf(v);
                } else if constexpr (EPI == EPI_BIAS_RES) {
                    if (SPLITK > 1 && blockIdx.z != 0) {
                        partial[(size_t)rg * NDIM + cg] = v;
                    } else {
                        v += bias[cg] + resid[(size_t)rg * NDIM + cg];
                        outF[(size_t)rg * NDIM + cg] = v;
                    }
                } else {
                    // fast GELU (tanh form via exp2)
                    v += bias[cg];
                    float u = 0.7978845608028654f * (v + 0.044715f * v * v * v);
                    float e = exp2f(2.8853900817779268f * u);
                    v = v - v / (1.0f + e);
                    out0[(size_t)rg * NDIM + cg] = f2bf(v);
                }
            }
}

// ---------------------------------------------------------------------------
// Causal flash attention, swapped-QK^T (max-free exp2 softmax).
// ---------------------------------------------------------------------------
__global__ __launch_bounds__(256, 4) void attn_kernel(
    const unsigned short* __restrict__ q,
    const unsigned short* __restrict__ k,
    const unsigned short* __restrict__ vt,
    unsigned short* __restrict__ o)
{
    __shared__ __align__(16) unsigned short sK[2][64 * 64];   // 16 KB
    __shared__ __align__(16) unsigned short sV[2][64 * 64];   // 16 KB
    __shared__ __align__(16) unsigned short pl[4][1024];      //  8 KB
    const int tid = threadIdx.x, lane = tid & 63, w = tid >> 6;

    // XCD-aware balanced remap
    const int x = blockIdx.x & 7, jb = blockIdx.x >> 3;
    const int bhl = jb & 3, ss = (jb >> 2) & 7, rr = jb >> 5;
    const int qt = (rr == 0) ? ss : (rr == 1) ? 15 - ss : (rr == 2) ? 16 + ss : 31 - ss;
    const int bh = x * 4 + bhl;

    const int qbase = qt * 64 + w * 16;
    const unsigned short* qp = q  + (size_t)bh * T_ * DH_;
    const unsigned short* kp = k  + (size_t)bh * T_ * DH_;
    const unsigned short* vp = vt + (size_t)bh * DH_ * T_;
    const int rsel = lane & 15, g = lane >> 4, koff = g * 8;
    const int slot0 = w * 64 + lane;
    const int swz = (rsel & 7) << 4;

    short8 bq[2];
#pragma unroll
    for (int ks = 0; ks < 2; ks++)
        bq[ks] = *reinterpret_cast<const short8*>(
            &qp[(size_t)(qbase + rsel) * DH_ + ks * 32 + koff]);

    float lr = 0.f;
    f32x4 oacc[4];
#pragma unroll
    for (int n = 0; n < 4; n++) oacc[n] = (f32x4){0.f, 0.f, 0.f, 0.f};

    const int nt = qt + 1;
    int cur = 0;

    auto stage = [&](int buf, int kv0) {
#pragma unroll
        for (int i = 0; i < 2; i++) {
            int slot = i * 256 + slot0;
            int row = slot >> 3, ch = slot & 7;
            int sc = ch ^ (row & 7);
            gload_lds16(&kp[(size_t)(kv0 + row) * DH_ + sc * 8], &sK[buf][(i * 256 + w * 64) * 8]);
            gload_lds16(&vp[(size_t)row * T_ + kv0 + sc * 8],    &sV[buf][(i * 256 + w * 64) * 8]);
        }
    };

    stage(0, 0);
    __syncthreads();

    unsigned short* plw = pl[w];
    for (int t = 0; t < nt; ++t) {
        const int kv0 = t * 64;
        if (t + 1 < nt) stage(cur ^ 1, (t + 1) * 64);
        f32x4 s4[4];
#pragma unroll
        for (int sub = 0; sub < 4; sub++) {
            short8 ak0 = *swz_frag(sK[cur], sub * 16 + rsel, 0, g);
            short8 ak1 = *swz_frag(sK[cur], sub * 16 + rsel, 1, g);
            f32x4 t0 = (f32x4){0.f, 0.f, 0.f, 0.f};
            t0 = __builtin_amdgcn_mfma_f32_16x16x32_bf16(ak0, bq[0], t0, 0, 0, 0);
            t0 = __builtin_amdgcn_mfma_f32_16x16x32_bf16(ak1, bq[1], t0, 0, 0, 0);
            s4[sub] = t0;
        }
        const int qg = qbase + rsel;
        if (t == nt - 1) {
#pragma unroll
            for (int sub = 0; sub < 4; sub++)
#pragma unroll
                for (int jj = 0; jj < 4; jj++) {
                    int kvg = kv0 + sub * 16 + g * 4 + jj;
                    if (kvg > qg) s4[sub][jj] = -1e30f;
                }
        }
#pragma unroll
        for (int sub = 0; sub < 4; sub++) {
            float p0 = exp2f(s4[sub][0]);
            float p1 = exp2f(s4[sub][1]);
            float p2 = exp2f(s4[sub][2]);
            float p3 = exp2f(s4[sub][3]);
            lr += (p0 + p1) + (p2 + p3);
            uint2 pk;
            pk.x = f2bf_trunc_u(p0) | (f2bf_trunc_u(p1) << 16);
            pk.y = f2bf_trunc_u(p2) | (f2bf_trunc_u(p3) << 16);
            int byte = rsel * 128 + ((sub * 32 + g * 8) ^ swz);
            *reinterpret_cast<uint2*>(reinterpret_cast<char*>(plw) + byte) = pk;
        }
#pragma unroll
        for (int ks = 0; ks < 2; ks++) {
            int rbyte = rsel * 128 + ((ks * 64 + g * 16) ^ swz);
            short8 bp = *reinterpret_cast<const short8*>(
                reinterpret_cast<const char*>(plw) + rbyte);
#pragma unroll
            for (int n = 0; n < 4; n++) {
                short8 av = *swz_frag(sV[cur], n * 16 + rsel, ks, g);
                oacc[n] = __builtin_amdgcn_mfma_f32_16x16x32_bf16(av, bp, oacc[n], 0, 0, 0);
            }
        }
        __syncthreads();
        cur ^= 1;
    }

    lr += __shfl_xor(lr, 16);
    lr += __shfl_xor(lr, 32);
    float inv = 1.0f / lr;
    const int bb = bh >> 4, h = bh & 15;
    const int rg = qbase + rsel;
    unsigned short* ob = o + ((size_t)(bb * T_ + rg)) * D_ + h * DH_ + g * 4;
#pragma unroll
    for (int n = 0; n < 4; n++) {
        uint2 pk;
        pk.x = (unsigned)f2bf(oacc[n][0] * inv) | ((unsigned)f2bf(oacc[n][1] * inv) << 16);
        pk.y = (unsigned)f2bf(oacc[n][2] * inv) | ((unsigned)f2bf(oacc[n][3] * inv) << 16);
        *reinterpret_cast<uint2*>(ob + n * 16) = pk;
    }
}

// ---------------------------------------------------------------------------
// Launch sequence
// ---------------------------------------------------------------------------
extern "C" void kernel_launch(void* const* d_in, const int* in_sizes, int n_in,
                              void* d_out, int out_size, void* d_ws, size_t ws_size,
                              hipStream_t stream)
{
    const float* x    = (const float*)d_in[0];
    const float* wq   = (const float*)d_in[1];
    const float* wk   = (const float*)d_in[2];
    const float* wv   = (const float*)d_in[3];
    const float* wo   = (const float*)d_in[4];
    const float* bo   = (const float*)d_in[5];
    const float* w1   = (const float*)d_in[6];
    const float* b1   = (const float*)d_in[7];
    const float* w2   = (const float*)d_in[8];
    const float* b2   = (const float*)d_in[9];
    const float* ln1s = (const float*)d_in[10];
    const float* ln1b = (const float*)d_in[11];
    const float* ln2s = (const float*)d_in[12];
    const float* ln2b = (const float*)d_in[13];
    float* out = (float*)d_out;

    char* ws = (char*)d_ws;
    unsigned short* wqkv_t = (unsigned short*)ws;                     // [3072][1024]
    unsigned short* wo_t   = wqkv_t + (size_t)3072 * 1024;            // [1024][1024]
    unsigned short* w1_t   = wo_t   + (size_t)1024 * 1024;            // [4096][1024]
    unsigned short* w2_t   = w1_t   + (size_t)4096 * 1024;            // [1024][4096]
    unsigned short* hbuf   = w2_t   + (size_t)1024 * 4096;            // [4096][1024]
    unsigned short* qb     = hbuf   + (size_t)4096 * 1024;            // (B,H,T,DH)
    unsigned short* kb     = qb     + (size_t)32 * 2048 * 64;
    unsigned short* vtb    = kb     + (size_t)32 * 2048 * 64;         // (B,H,DH,T)
    unsigned short* ao     = vtb    + (size_t)32 * 64 * 2048;         // (B,T,D)
    unsigned short* f1     = qb;    // reuse q|k|vt|ao span after attention+WO
    float* fpart = (float*)ws;      // overlays dead wqkv_t..w1_t at FF2 time

    // weight converts (wq folded with 0.125 * log2(e) for exp2-domain softmax)
    cvt_t4_kernel<<<dim3(16, 16, 4), 256, 0, stream>>>(
        wq, wk, wv, wo,
        wqkv_t, wqkv_t + 1024 * 1024, wqkv_t + 2 * 1024 * 1024, wo_t,
        0.180336880111120425f);
    cvt_t_kernel<<<dim3(16, 64), 256, 0, stream>>>(w1, w1_t, 1024, 4096, 1.f);
    cvt_t_kernel<<<dim3(64, 16), 256, 0, stream>>>(w2, w2_t, 4096, 1024, 1.f);

    // attention sublayer
    ln_kernel<<<M_, 256, 0, stream>>>(x, ln1s, ln1b, hbuf);
    gemm_nt<EPI_QKV3, 1024, 3072, 0, 64, 1><<<dim3(64, 24), 256, 0, stream>>>(
        hbuf, wqkv_t, qb, kb, vtb, nullptr, nullptr, nullptr, nullptr);
    attn_kernel<<<1024, 256, 0, stream>>>(qb, kb, vtb, ao);
    gemm_nt<EPI_BIAS_RES, 1024, 1024, 1, 64, 1><<<dim3(64, 8), 256, 0, stream>>>(
        ao, wo_t, nullptr, nullptr, nullptr, out, bo, x, nullptr);   // out = x2
    // feed-forward sublayer
    ln_kernel<<<M_, 256, 0, stream>>>(out, ln2s, ln2b, hbuf);
    gemm_ff1_wide<<<dim3(16, 32), 256, 0, stream>>>(hbuf, w1_t, f1, b1);
    gemm_nt<EPI_BIAS_RES, 4096, 1024, 0, 64, 2><<<dim3(64, 8, 2), 256, 0, stream>>>(
        f1, w2_t, nullptr, nullptr, nullptr, out, b2, out, fpart);   // z=0: out, z=1: fpart
    addp_kernel<<<2048, 256, 0, stream>>>(out, fpart);               // out += fpart
}